// Round 9
// baseline (157.630 us; speedup 1.0000x reference)
//
#include <hip/hip_runtime.h>
#include <stdint.h>

typedef __bf16 bf16x8 __attribute__((ext_vector_type(8)));
typedef float floatx4 __attribute__((ext_vector_type(4)));
typedef float floatx4u __attribute__((ext_vector_type(4), aligned(4)));
typedef unsigned int u32x4 __attribute__((ext_vector_type(4)));
typedef unsigned short u16;
typedef unsigned int u32;

#define CIN   64
#define COUT  128
#define H_    1855
#define KNB   6
#define KTOT  448      // (1+KNB)*CIN
#define NSTEPS 14      // KTOT / 32

// ws layout (bytes). srcOff[h][8]: s=0..6 resolved row byte-offsets (invalid
// neighbor -> ZROW_OFF, an 8-KB zero row), s=7 = f32 bits of 1/count.
#define WP_OFF     ((size_t)H_ * 4096 * 2)                 // xt3: bf16 [h][4096]
#define SRCOFF_OFF (WP_OFF + (size_t)COUT * KTOT * 2)      // u32 [H][8]
#define ZROW_OFF   (SRCOFF_OFF + 59392)                    // 8-KB zero row

#define PIN4(v) asm volatile("" : "+v"(v))

static __device__ inline u16 f32_to_bf16(float f) {
    u32 u = __float_as_uint(f);
    u32 r = (u + 0x7FFFu + ((u >> 16) & 1u)) >> 16;
    return (u16)r;
}

// ---- K1 (fused): transpose x f32 [bc][h] -> xt3 bf16 [h][bc], plus
// weight-pack / zero-row / resolved gather-offset table (cInv in slot 7).
__global__ __launch_bounds__(256) void k_prep(const float* __restrict__ x,
                                              const float* __restrict__ wc,
                                              const float* __restrict__ wn,
                                              const int* __restrict__ nbr,
                                              u16* __restrict__ xt3,
                                              u16* __restrict__ wp,
                                              u32* __restrict__ srcOff2,
                                              u32* __restrict__ zrow) {
    int tid = threadIdx.x;
    if (blockIdx.y == 64) {            // ---- pack stripe (29 blocks, strided)
        for (int tg = blockIdx.x * 256 + tid; tg < COUT * KTOT; tg += 29 * 256) {
            if (tg < 2048) zrow[tg] = 0u;            // 8-KB zero row
            if (tg < H_ * 8) {
                int h = tg >> 3, s = tg & 7;
                u32 e;
                if (s == 0) e = (u32)h * 8192u;
                else if (s <= 6) {
                    int n = nbr[h * KNB + (s - 1)];
                    e = (n >= 0) ? (u32)n * 8192u : (u32)ZROW_OFF;
                } else {                             // s == 7: 1/count bits
                    int cnt = 1;
#pragma unroll
                    for (int j = 0; j < KNB; ++j) cnt += (nbr[h * KNB + j] >= 0) ? 1 : 0;
                    e = __float_as_uint(1.0f / (float)cnt);
                }
                srcOff2[tg] = e;
            }
            int o = tg / KTOT;
            int rem = tg - o * KTOT;
            int s = rem >> 6, c = rem & 63;
            float v = (s == 0) ? wc[o * CIN + c]
                               : wn[(o * CIN + c) * KNB + (s - 1)];
            wp[tg] = f32_to_bf16(v);
        }
        return;
    }
    // ---- transpose stripe: tile = u32 (bc even|odd packed), stride 34
    __shared__ u32 t32[64][34];
    int h0  = blockIdx.x * 64;
    int bc0 = blockIdx.y * 64;
    int lh = tid & 15;                 // h-quad (4 h per thread)
    int rq = tid >> 4;                 // 0..15 rowpair sub-index
    bool safe = (h0 + 64 <= H_);
#pragma unroll
    for (int it = 0; it < 2; ++it) {
        int rp = it * 16 + rq;         // rowpair 0..31 -> rows 2rp, 2rp+1
        size_t r0 = (size_t)(bc0 + rp * 2) * H_;
        size_t r1 = r0 + H_;
        int h = h0 + lh * 4;
        u32 p[4];
        if (safe) {
            floatx4u f0 = *(const floatx4u*)(x + r0 + h);
            floatx4u f1 = *(const floatx4u*)(x + r1 + h);
#pragma unroll
            for (int j = 0; j < 4; ++j)
                p[j] = (u32)f32_to_bf16(f0[j]) | ((u32)f32_to_bf16(f1[j]) << 16);
        } else {
#pragma unroll
            for (int j = 0; j < 4; ++j) {
                int hh = h + j;
                u16 a = 0, b = 0;
                if (hh < H_) { a = f32_to_bf16(x[r0 + hh]); b = f32_to_bf16(x[r1 + hh]); }
                p[j] = (u32)a | ((u32)b << 16);
            }
        }
#pragma unroll
        for (int j = 0; j < 4; ++j) t32[lh * 4 + j][rp] = p[j];
    }
    __syncthreads();
    int bg = tid & 7;                  // bc-octet
    int hb = tid >> 3;                 // 0..31
#pragma unroll
    for (int ii = 0; ii < 2; ++ii) {
        int hl = ii * 32 + hb;
        int hh = h0 + hl;
        uint2 qa = *(const uint2*)&t32[hl][bg * 4];
        uint2 qb = *(const uint2*)&t32[hl][bg * 4 + 2];
        u32x4 q = {qa.x, qa.y, qb.x, qb.y};
        if (hh < H_)
            *(u32x4*)(xt3 + (size_t)hh * 4096 + bc0 + bg * 8) = q;
    }
}

// ---- K3: BARRIER-FREE direct-register-gather GEMM -------------------------
// grid = 512 persistent (32 bp x 16 slots, XCD = gbl&7, bp pinned). Block =
// 4 INDEPENDENT waves (no __shared__, no s_barrier, no block coupling): each
// wave computes M=32 x (64h x 2b) per hs. B-fragments load DIRECTLY from xt3
// into VGPRs: per k-step kk, 2 global_load_dwordx4 at rcc[kk>>1] + imm —
// the c-contiguous 16 B is exactly the MFMA k-fragment. Flat 56-step pipeline
// (4 tiles x 14 kk): loads issued 4 steps ahead into slot (g&3); index rows
// for tile t+1 prefetched at tile-t start, resolved at kk=9; cross-hs
// prefetch at tile-3 start. Compiler emits per-use counted vmcnt. Epilogue
// pairs tiles (t,t+1): both 64-B halves of each 128-B out-line stored
// back-to-back. ~225 VGPR < 256 cap of (256,2) — do not raise min-waves.
__global__ __launch_bounds__(256, 2) void k_main(const u16* __restrict__ xt3,
                                                 const u16* __restrict__ wp,
                                                 const float* __restrict__ bias,
                                                 const u32* __restrict__ srcOff,
                                                 float* __restrict__ out) {
    int tid  = threadIdx.x;
    int gbl  = blockIdx.x;
    int bp   = gbl & 31;          // b-pair, fixed; XCD = bp&7
    int slot = gbl >> 5;          // 0..15
    int b0   = bp * 2;

    int lane = tid & 63;
    int wave = tid >> 6;          // 0..3
    int col  = lane & 15;
    int quad = lane >> 4;
    int m0w  = wave * 32;

    const char* xb = (const char*)xt3;   // == d_ws base; offsets relative

    // A fragments (weights): A[m=col][k=quad*8+j]; 112 regs, pinned.
    u32x4 afrag[2][NSTEPS];
#pragma unroll
    for (int mt = 0; mt < 2; ++mt) {
        int o = m0w + mt * 16 + col;
#pragma unroll
        for (int kk = 0; kk < NSTEPS; ++kk)
            afrag[mt][kk] = *(const u32x4*)(wp + o * KTOT + kk * 32 + quad * 8);
    }
#pragma unroll
    for (int mt = 0; mt < 2; ++mt)
#pragma unroll
        for (int kk = 0; kk < NSTEPS; ++kk)
            PIN4(afrag[mt][kk]);

    float biasv[2][4];
#pragma unroll
    for (int mt = 0; mt < 2; ++mt)
#pragma unroll
        for (int r = 0; r < 4; ++r)
            biasv[mt][r] = bias[m0w + mt * 16 + quad * 4 + r];

    u32 cc = (u32)(b0 * 128 + quad * 16);   // lane's (b,c) slice within a row

    u32x4 bb[4][2];              // B pipeline: 4 slots x 2 nt
    u32x4 rn01, rn23;            // prefetched srcOff row for next tile
    u32 rccA[7], rccB[7];        // resolved per-lane row offsets (+cc)
    float ic0, ic1, ic2, ic3;
    floatx4 accE[2][2], accO[2][2];

#define IPRF(hbase) do {                                                      \
    int _hq = (hbase) + col; int _hcl = _hq < H_ ? _hq : H_ - 1;              \
    const u32* _st = srcOff + (size_t)_hcl * 8;                               \
    rn01 = *(const u32x4*)_st; rn23 = *(const u32x4*)(_st + 4);               \
} while (0)

#define RBUILD(RCC, ICV) do {                                                 \
    RCC[0] = rn01[0] + cc; RCC[1] = rn01[1] + cc;                             \
    RCC[2] = rn01[2] + cc; RCC[3] = rn01[3] + cc;                             \
    RCC[4] = rn23[0] + cc; RCC[5] = rn23[1] + cc; RCC[6] = rn23[2] + cc;      \
    ICV = __uint_as_float(rn23[3]);                                           \
} while (0)

#define BLOAD(k2, sl, RCC) do {                                               \
    u32 _o = RCC[(k2) >> 1] + (u32)(((k2) & 1) * 64);                         \
    bb[sl][0] = *(const u32x4*)(xb + _o);                                     \
    bb[sl][1] = *(const u32x4*)(xb + _o + 128);                               \
} while (0)

#define MF4(g, ACC) do {                                                      \
    const int _kk = (g) % 14, _sl = (g) & 3;                                  \
    bf16x8 _ba = __builtin_bit_cast(bf16x8, bb[_sl][0]);                      \
    bf16x8 _bb = __builtin_bit_cast(bf16x8, bb[_sl][1]);                      \
    bf16x8 _a0 = __builtin_bit_cast(bf16x8, afrag[0][_kk]);                   \
    bf16x8 _a1 = __builtin_bit_cast(bf16x8, afrag[1][_kk]);                   \
    ACC[0][0] = __builtin_amdgcn_mfma_f32_16x16x32_bf16(_a0, _ba, ACC[0][0], 0, 0, 0); \
    ACC[1][0] = __builtin_amdgcn_mfma_f32_16x16x32_bf16(_a1, _ba, ACC[1][0], 0, 0, 0); \
    ACC[0][1] = __builtin_amdgcn_mfma_f32_16x16x32_bf16(_a0, _bb, ACC[0][1], 0, 0, 0); \
    ACC[1][1] = __builtin_amdgcn_mfma_f32_16x16x32_bf16(_a1, _bb, ACC[1][1], 0, 0, 0); \
} while (0)

// step g: MFMA on slot g&3, then refill same slot for step g+4.
#define STEP_L(g, ACC, RCC) do { MF4(g, ACC); BLOAD(((g) + 4) % 14, ((g) + 4) & 3, RCC); } while (0)

#define ZACC(A) do {                                                          \
    A[0][0] = (floatx4){0,0,0,0}; A[0][1] = (floatx4){0,0,0,0};               \
    A[1][0] = (floatx4){0,0,0,0}; A[1][1] = (floatx4){0,0,0,0};               \
} while (0)

// Pair epilogue: tiles (2pp, 2pp+1) -> both 64-B halves of each 128-B line
// back-to-back (write-merge). BND masks only h=1855 (hs=28, t=3, col=15).
#define EPIPAIR(pp, icEv, icOv, BND) do {                                     \
    int _hA = h0 + (pp) * 32 + col;                                           \
    bool _hBv = !(BND) || (_hA + 16 < H_);                                    \
    _Pragma("unroll") for (int _nt = 0; _nt < 2; ++_nt)                       \
    _Pragma("unroll") for (int _mt = 0; _mt < 2; ++_mt)                       \
    _Pragma("unroll") for (int _rr = 0; _rr < 4; ++_rr) {                     \
        int _o = m0w + _mt * 16 + quad * 4 + _rr;                             \
        float* _p = out + ((size_t)(b0 + _nt) * COUT + _o) * H_ + _hA;        \
        _p[0] = accE[_mt][_nt][_rr] * (icEv) + biasv[_mt][_rr];               \
        if (_hBv) _p[16] = accO[_mt][_nt][_rr] * (icOv) + biasv[_mt][_rr];    \
    }                                                                         \
} while (0)

    IPRF(slot * 64);              // idx rows for first hs, tile 0

    for (int hs = slot; hs <= 28; hs += 16) {
        int h0 = hs * 64;
        bool bnd = (hs == 28);

        RBUILD(rccA, ic0);
        BLOAD(0, 0, rccA); BLOAD(1, 1, rccA); BLOAD(2, 2, rccA); BLOAD(3, 3, rccA);

        // ---- tile 0 (g = 0..13, accE, cur rccA -> next rccB) ----
        ZACC(accE);
        STEP_L(0, accE, rccA);  IPRF(h0 + 16);
        STEP_L(1, accE, rccA);  STEP_L(2, accE, rccA);  STEP_L(3, accE, rccA);
        STEP_L(4, accE, rccA);  STEP_L(5, accE, rccA);  STEP_L(6, accE, rccA);
        STEP_L(7, accE, rccA);  STEP_L(8, accE, rccA);  STEP_L(9, accE, rccA);
        RBUILD(rccB, ic1);
        STEP_L(10, accE, rccB); STEP_L(11, accE, rccB);
        STEP_L(12, accE, rccB); STEP_L(13, accE, rccB);

        // ---- tile 1 (g = 14..27, accO, cur rccB -> next rccA) ----
        ZACC(accO);
        STEP_L(14, accO, rccB); IPRF(h0 + 32);
        STEP_L(15, accO, rccB); STEP_L(16, accO, rccB); STEP_L(17, accO, rccB);
        STEP_L(18, accO, rccB); STEP_L(19, accO, rccB); STEP_L(20, accO, rccB);
        STEP_L(21, accO, rccB); STEP_L(22, accO, rccB); STEP_L(23, accO, rccB);
        RBUILD(rccA, ic2);
        STEP_L(24, accO, rccA); STEP_L(25, accO, rccA);
        STEP_L(26, accO, rccA); STEP_L(27, accO, rccA);

        EPIPAIR(0, ic0, ic1, false);

        // ---- tile 2 (g = 28..41, accE, cur rccA -> next rccB) ----
        ZACC(accE);
        STEP_L(28, accE, rccA); IPRF(h0 + 48);
        STEP_L(29, accE, rccA); STEP_L(30, accE, rccA); STEP_L(31, accE, rccA);
        STEP_L(32, accE, rccA); STEP_L(33, accE, rccA); STEP_L(34, accE, rccA);
        STEP_L(35, accE, rccA); STEP_L(36, accE, rccA); STEP_L(37, accE, rccA);
        RBUILD(rccB, ic3);
        STEP_L(38, accE, rccB); STEP_L(39, accE, rccB);
        STEP_L(40, accE, rccB); STEP_L(41, accE, rccB);

        // ---- tile 3 (g = 42..55, accO; prefetch next hs) ----
        ZACC(accO);
        STEP_L(42, accO, rccB); IPRF(h0 + 1024);   // next hs tile-0 rows
        STEP_L(43, accO, rccB); STEP_L(44, accO, rccB); STEP_L(45, accO, rccB);
        STEP_L(46, accO, rccB); STEP_L(47, accO, rccB); STEP_L(48, accO, rccB);
        STEP_L(49, accO, rccB); STEP_L(50, accO, rccB); STEP_L(51, accO, rccB);
        MF4(52, accO); MF4(53, accO); MF4(54, accO); MF4(55, accO);

        EPIPAIR(1, ic2, ic3, bnd);
    }

#undef IPRF
#undef RBUILD
#undef BLOAD
#undef MF4
#undef STEP_L
#undef ZACC
#undef EPIPAIR
}

extern "C" void kernel_launch(void* const* d_in, const int* in_sizes, int n_in,
                              void* d_out, int out_size, void* d_ws, size_t ws_size,
                              hipStream_t stream) {
    const float* x    = (const float*)d_in[0];   // f32 [64,64,1855]
    const int*   nbr  = (const int*)d_in[1];     // int32 [1855,6]
    const float* wc   = (const float*)d_in[2];   // f32 [128,64]
    const float* wn   = (const float*)d_in[3];   // f32 [128,64,6]
    const float* bias = (const float*)d_in[4];   // f32 [128]

    u16* xt3    = (u16*)d_ws;
    u16* wp     = (u16*)((char*)d_ws + WP_OFF);
    u32* srcOff = (u32*)((char*)d_ws + SRCOFF_OFF);
    u32* zrow   = (u32*)((char*)d_ws + ZROW_OFF);

    k_prep<<<dim3(29, 65), dim3(256), 0, stream>>>(
        x, wc, wn, nbr, xt3, wp, srcOff, zrow);
    k_main<<<dim3(512), dim3(256), 0, stream>>>(
        xt3, wp, bias, srcOff, (float*)d_out);
}

// Round 10
// 139.438 us; speedup vs baseline: 1.1305x; 1.1305x over previous
//
#include <hip/hip_runtime.h>
#include <stdint.h>

typedef __bf16 bf16x8 __attribute__((ext_vector_type(8)));
typedef float floatx4 __attribute__((ext_vector_type(4)));
typedef float floatx4u __attribute__((ext_vector_type(4), aligned(4)));
typedef unsigned int u32x4 __attribute__((ext_vector_type(4)));
typedef unsigned short u16;
typedef unsigned int u32;

#define CIN   64
#define COUT  128
#define H_    1855
#define KNB   6
#define KTOT  448      // (1+KNB)*CIN
#define NSTEPS 14      // KTOT / 32

// Half-buffer (R3-verified geometry): 16 hl rows x 4 s-slots; row = 1040 B.
// THREE rotating buffers = 49920 B -> 3 blocks/CU (the point of this round).
#define HROW   1040
#define HBUFSZ 16640   // 16 * HROW

// ws layout (bytes). wp2 = K-MAJOR packed weights: 16-B chunk index
// ((kk*8 + ot)*64 + lane) holds A[o=ot*16+(lane&15)][k=kk*32+(lane>>4)*8+j].
#define WP_OFF     ((size_t)H_ * 4096 * 2)                 // xt3: bf16 [h][4096]
#define CINV_OFF   (WP_OFF + (size_t)COUT * KTOT * 2)
#define ZERO_OFF   (CINV_OFF + 7424)                       // 512-B zero page
#define SRCOFF_OFF (ZERO_OFF + 1024)                       // u32 [H][8] gather row offsets
#define INVOFF 0xFFFFFFFFu

typedef __attribute__((address_space(1))) unsigned int as1_u32;
typedef __attribute__((address_space(3))) unsigned int as3_u32;
static __device__ __forceinline__ void ld16_to_lds(const void* g, void* l) {
    __builtin_amdgcn_global_load_lds((const as1_u32*)g, (as3_u32*)l, 16, 0, 0);
}

static __device__ inline u16 f32_to_bf16(float f) {
    u32 u = __float_as_uint(f);
    u32 r = (u + 0x7FFFu + ((u >> 16) & 1u)) >> 16;
    return (u16)r;
}

// ---- K1 (fused): transpose x -> xt3 bf16 [h][bc], weight K-MAJOR pack,
// inverse counts, zero page, gather-offset table.
__global__ __launch_bounds__(256) void k_prep(const float* __restrict__ x,
                                              const float* __restrict__ wc,
                                              const float* __restrict__ wn,
                                              const int* __restrict__ nbr,
                                              u16* __restrict__ xt3,
                                              u16* __restrict__ wp2,
                                              float* __restrict__ cInvG,
                                              u32* __restrict__ zeroPg,
                                              u32* __restrict__ srcOff) {
    int tid = threadIdx.x;
    if (blockIdx.y == 64) {            // ---- pack stripe (29 blocks, strided)
        for (int tg = blockIdx.x * 256 + tid; tg < COUT * KTOT; tg += 29 * 256) {
            if (tg < 128) zeroPg[tg] = 0u;           // 512-B zero page
            if (tg < H_) {
                int cnt = 1;
#pragma unroll
                for (int j = 0; j < KNB; ++j) cnt += (nbr[tg * KNB + j] >= 0) ? 1 : 0;
                cInvG[tg] = 1.0f / (float)cnt;
            }
            if (tg < H_ * 8) {
                int h = tg >> 3, s = tg & 7;
                u32 e;
                if (s == 0) e = (u32)h * 8192u;
                else if (s <= 6) {
                    int n = nbr[h * KNB + (s - 1)];
                    e = (n >= 0) ? (u32)n * 8192u : INVOFF;
                } else e = INVOFF;
                srcOff[tg] = e;
            }
            // K-major pack: tg = DEST element; invert to (o, k).
            int j    = tg & 7;
            int ln   = (tg >> 3) & 63;        // lane
            int ot   = (tg >> 9) & 7;         // o-tile
            int kk   = tg >> 12;              // k-step 0..13
            int o    = ot * 16 + (ln & 15);
            int k    = kk * 32 + (ln >> 4) * 8 + j;
            int s    = k >> 6, c = k & 63;
            float v = (s == 0) ? wc[o * CIN + c]
                               : wn[(o * CIN + c) * KNB + (s - 1)];
            wp2[tg] = f32_to_bf16(v);
        }
        return;
    }
    // ---- transpose stripe: tile = u32 (bc even|odd packed), stride 34
    __shared__ u32 t32[64][34];
    int h0  = blockIdx.x * 64;
    int bc0 = blockIdx.y * 64;
    int lh = tid & 15;                 // h-quad (4 h per thread)
    int rq = tid >> 4;                 // 0..15 rowpair sub-index
    bool safe = (h0 + 64 <= H_);
#pragma unroll
    for (int it = 0; it < 2; ++it) {
        int rp = it * 16 + rq;         // rowpair 0..31 -> rows 2rp, 2rp+1
        size_t r0 = (size_t)(bc0 + rp * 2) * H_;
        size_t r1 = r0 + H_;
        int h = h0 + lh * 4;
        u32 p[4];
        if (safe) {
            floatx4u f0 = *(const floatx4u*)(x + r0 + h);
            floatx4u f1 = *(const floatx4u*)(x + r1 + h);
#pragma unroll
            for (int j = 0; j < 4; ++j)
                p[j] = (u32)f32_to_bf16(f0[j]) | ((u32)f32_to_bf16(f1[j]) << 16);
        } else {
#pragma unroll
            for (int j = 0; j < 4; ++j) {
                int hh = h + j;
                u16 a = 0, b = 0;
                if (hh < H_) { a = f32_to_bf16(x[r0 + hh]); b = f32_to_bf16(x[r1 + hh]); }
                p[j] = (u32)a | ((u32)b << 16);
            }
        }
#pragma unroll
        for (int j = 0; j < 4; ++j) t32[lh * 4 + j][rp] = p[j];
    }
    __syncthreads();
    int bg = tid & 7;                  // bc-octet
    int hb = tid >> 3;                 // 0..31
#pragma unroll
    for (int ii = 0; ii < 2; ++ii) {
        int hl = ii * 32 + hb;
        int hh = h0 + hl;
        uint2 qa = *(const uint2*)&t32[hl][bg * 4];
        uint2 qb = *(const uint2*)&t32[hl][bg * 4 + 2];
        u32x4 q = {qa.x, qa.y, qb.x, qb.y};
        if (hh < H_)
            *(u32x4*)(xt3 + (size_t)hh * 4096 + bc0 + bg * 8) = q;
    }
}

// ---- K3: A-STREAMING gather-GEMM, 3 blocks/CU ----------------------------
// grid = 928 = 29 hs x 32 bp (XCD = g&7). Block = 4 waves, M=32/wave, but
// NO resident A-fragments: A streams per k-step from the K-major wp2 (L2-hot
// 115 KB, 1-KB coalesced wave reads) -> per-wave live ~130 regs -> fits the
// 170-reg cap of (256,3). LDS = 3 rotating half-buffers (49.9 KB) -> 3
// blocks/CU = 12 waves/CU (+50% TLP at IDENTICAL gather volume — the combo
// R7's om-split could not reach). Counted-vmcnt ladder re-derived for the
// 3-buffer FIFO; per-tile direct-store epilogue (race-free with rotation).
__global__ __launch_bounds__(256, 3) void k_main(const u16* __restrict__ xt3,
                                                 const u16* __restrict__ wp2,
                                                 const float* __restrict__ bias,
                                                 const float* __restrict__ cInvG,
                                                 const u32* __restrict__ srcOff,
                                                 float* __restrict__ out) {
    __shared__ __align__(16) char LDS[3 * HBUFSZ];

    int tid  = threadIdx.x;
    int gbl  = blockIdx.x;
    int bp   = gbl & 31;          // b-pair; XCD = gbl&7
    int hs   = gbl >> 5;          // 0..28
    int b0   = bp * 2;
    int h0   = hs * 64;

    int lane = tid & 63;
    int wave = tid >> 6;          // 0..3
    int col  = lane & 15;
    int quad = lane >> 4;
    int m0w  = wave * 32;
    int lane16 = lane & 15;
    int ssub = lane >> 4;
    int bl   = lane16 >> 3;
    int chunk = lane16 & 7;

    const char* xb  = (const char*)xt3;            // staging base (== d_ws)
    const char* wpb = (const char*)wp2 + wave * 2048 + lane * 16;  // A stream base

    float biasv[2][4];
#pragma unroll
    for (int mt = 0; mt < 2; ++mt)
#pragma unroll
        for (int r = 0; r < 4; ++r)
            biasv[mt][r] = bias[m0w + mt * 16 + quad * 4 + r];

    float icv[4];
#pragma unroll
    for (int t = 0; t < 4; ++t) {
        int hic = h0 + t * 16 + col;
        icv[t] = cInvG[hic < H_ ? hic : 0];
    }

    u32 colOff = (u32)((b0 + bl) * 128 + chunk * 16);
    u32 zOff   = (u32)ZERO_OFF + (u32)(lane16 * 16);
    u32 offs[4][2][4];
#pragma unroll
    for (int t = 0; t < 4; ++t)
#pragma unroll
        for (int sg = 0; sg < 2; ++sg)
#pragma unroll
            for (int i = 0; i < 4; ++i) {
                int hh = h0 + t * 16 + wave * 4 + i;
                int s  = sg * 4 + ssub;
                u32 e = (hh < H_) ? srcOff[hh * 8 + s] : INVOFF;
                offs[t][sg][i] = (e == INVOFF) ? zOff : (e + colOff);
            }

    int rb0 = col * HROW + quad * 16;
    int rb1 = rb0 + 128;
    char* B0 = LDS;
    char* B1 = LDS + HBUFSZ;
    char* B2 = LDS + 2 * HBUFSZ;
    bool bnd = (hs == 28);

#define SGH(t, sg, bufp) do {                                                 \
    char* _d = (bufp) + (wave * 4) * HROW;                                    \
    _Pragma("unroll")                                                         \
    for (int _i = 0; _i < 4; ++_i)                                            \
        ld16_to_lds(xb + offs[t][sg][_i], _d + _i * HROW);                    \
} while (0)

// One k-step: 2 coalesced A loads (L2-hot wp2) + 2 LDS B reads + 4 MFMA.
#define KSTEP(accv, bufp, kk, koff) do {                                      \
    u32x4 _a0r = *(const u32x4*)(wpb + (kk) * 8192);                          \
    u32x4 _a1r = *(const u32x4*)(wpb + (kk) * 8192 + 1024);                   \
    bf16x8 _ba = *(const bf16x8*)((bufp) + rb0 + (koff));                     \
    bf16x8 _bb = *(const bf16x8*)((bufp) + rb1 + (koff));                     \
    bf16x8 _a0 = __builtin_bit_cast(bf16x8, _a0r);                            \
    bf16x8 _a1 = __builtin_bit_cast(bf16x8, _a1r);                            \
    accv[0][0] = __builtin_amdgcn_mfma_f32_16x16x32_bf16(_a0, _ba, accv[0][0], 0, 0, 0); \
    accv[1][0] = __builtin_amdgcn_mfma_f32_16x16x32_bf16(_a1, _ba, accv[1][0], 0, 0, 0); \
    accv[0][1] = __builtin_amdgcn_mfma_f32_16x16x32_bf16(_a0, _bb, accv[0][1], 0, 0, 0); \
    accv[1][1] = __builtin_amdgcn_mfma_f32_16x16x32_bf16(_a1, _bb, accv[1][1], 0, 0, 0); \
} while (0)

#define CA(accv, bufp) do {  /* k-steps 0..7, zero-init */                    \
    _Pragma("unroll") for (int _m = 0; _m < 2; ++_m)                          \
    _Pragma("unroll") for (int _n = 0; _n < 2; ++_n)                          \
        accv[_m][_n] = (floatx4){0.0f, 0.0f, 0.0f, 0.0f};                     \
    __builtin_amdgcn_s_setprio(1);                                            \
    _Pragma("unroll")                                                         \
    for (int kk = 0; kk < 8; ++kk)                                            \
        KSTEP(accv, bufp, kk, (kk >> 1) * 256 + (kk & 1) * 64);               \
    __builtin_amdgcn_s_setprio(0);                                            \
} while (0)

#define CB(accv, bufp) do {  /* k-steps 8..13, accumulate */                  \
    __builtin_amdgcn_s_setprio(1);                                            \
    _Pragma("unroll")                                                         \
    for (int kk = 8; kk < 14; ++kk)                                           \
        KSTEP(accv, bufp, kk, ((kk - 8) >> 1) * 256 + (kk & 1) * 64);         \
    __builtin_amdgcn_s_setprio(0);                                            \
} while (0)

// Per-tile direct-store epilogue: 16 stores/lane (64-B segments), no LDS.
// Only the final (uncounted) EPI masks the single ragged lane at h=1855.
#define EPI(t, accv, BND) do {                                                \
    int _h = h0 + (t) * 16 + col;                                             \
    float _ic = icv[t];                                                       \
    bool _hv = !(BND) || (_h < H_);                                           \
    _Pragma("unroll") for (int _n = 0; _n < 2; ++_n)                          \
    _Pragma("unroll") for (int _mt = 0; _mt < 2; ++_mt)                       \
    _Pragma("unroll") for (int _r = 0; _r < 4; ++_r) {                        \
        int _o = m0w + _mt * 16 + quad * 4 + _r;                              \
        float _v = accv[_mt][_n][_r] * _ic + biasv[_mt][_r];                  \
        if (_hv) out[(size_t)(b0 + _n) * ((size_t)COUT * H_)                  \
                     + (size_t)_o * H_ + _h] = _v;                            \
    }                                                                         \
} while (0)

#define VW(n)  asm volatile("s_waitcnt vmcnt(" #n ") lgkmcnt(0)" ::: "memory")
#define BAR()  __builtin_amdgcn_s_barrier()

    floatx4 acc[2][2];

    // Stage k (t=k>>1, sg=k&1) -> buffer k%3. FIFO counts below consider
    // only SGH (4) and EPI stores (16); interleaved A-loads only make the
    // waits more conservative (safe: in-order retirement).
    SGH(0, 0, B0); SGH(0, 1, B1);                        // [S0][S1]
    VW(4);  BAR(); SGH(1, 0, B2); CA(acc, B0);           // ph0: needs S0
    VW(4);  BAR(); SGH(1, 1, B0); CB(acc, B1);           // ph1: needs S1
    EPI(0, acc, false);                                  //   +16 stores
    VW(20); BAR(); SGH(2, 0, B1); CA(acc, B2);           // ph2: needs S2 (S3+E0=20)
    VW(20); BAR(); SGH(2, 1, B2); CB(acc, B0);           // ph3: needs S3 (E0+S4=20)
    EPI(1, acc, false);
    VW(20); BAR(); SGH(3, 0, B0); CA(acc, B1);           // ph4: needs S4 (S5+E1=20; drains E0 aged 3)
    VW(20); BAR(); SGH(3, 1, B1); CB(acc, B2);           // ph5: needs S5 (E1+S6=20)
    EPI(2, acc, false);
    VW(20); BAR();                CA(acc, B0);           // ph6: needs S6 (S7+E2=20; drains E1 aged 3)
    VW(16); BAR();                CB(acc, B1);           // ph7: needs S7 (E2=16)
    EPI(3, acc, bnd);                                    //   drains at endpgm

#undef SGH
#undef KSTEP
#undef CA
#undef CB
#undef EPI
#undef VW
#undef BAR
}

extern "C" void kernel_launch(void* const* d_in, const int* in_sizes, int n_in,
                              void* d_out, int out_size, void* d_ws, size_t ws_size,
                              hipStream_t stream) {
    const float* x    = (const float*)d_in[0];   // f32 [64,64,1855]
    const int*   nbr  = (const int*)d_in[1];     // int32 [1855,6]
    const float* wc   = (const float*)d_in[2];   // f32 [128,64]
    const float* wn   = (const float*)d_in[3];   // f32 [128,64,6]
    const float* bias = (const float*)d_in[4];   // f32 [128]

    u16*   xt3    = (u16*)d_ws;
    u16*   wp2    = (u16*)((char*)d_ws + WP_OFF);
    float* cInvG  = (float*)((char*)d_ws + CINV_OFF);
    u32*   zeroPg = (u32*)((char*)d_ws + ZERO_OFF);
    u32*   srcOff = (u32*)((char*)d_ws + SRCOFF_OFF);

    k_prep<<<dim3(29, 65), dim3(256), 0, stream>>>(
        x, wc, wn, nbr, xt3, wp2, cInvG, zeroPg, srcOff);
    k_main<<<dim3(928), dim3(256), 0, stream>>>(
        xt3, wp2, bias, cInvG, srcOff, (float*)d_out);
}

// Round 11
// 125.360 us; speedup vs baseline: 1.2574x; 1.1123x over previous
//
#include <hip/hip_runtime.h>
#include <stdint.h>

typedef __bf16 bf16x8 __attribute__((ext_vector_type(8)));
typedef float floatx4 __attribute__((ext_vector_type(4)));
typedef float floatx4u __attribute__((ext_vector_type(4), aligned(4)));
typedef unsigned int u32x4 __attribute__((ext_vector_type(4)));
typedef unsigned short u16;
typedef unsigned int u32;

#define CIN   64
#define COUT  128
#define H_    1855
#define KNB   6
#define KTOT  448      // (1+KNB)*CIN
#define NSTEPS 14      // KTOT / 32

// xt3 row pitch: 8448 B = 33*256 (NOT 8192). Power-of-2 pitch put every
// gathered 256-B slice at identical low address bits -> all traffic camped
// on 1-2 L2/TCC channels (the schedule-invariant ~6.4k cyc/phase wall seen
// R1..R10). 8448 mod 4096 = 256 -> rows rotate across channel slots at any
// interleave granularity. Rows use first 8192 B; 256-B tail uninitialized.
#define XPITCH  8448
#define XPITCH2 4224   // pitch in u16

// Half-buffer geometry (R3-verified): half-tile = 16 hl rows x 4 s-slots.
// Row = 4*256+16 pad = 1040 B. 4 rotating half-buffers.
#define HROW   1040
#define HBUFSZ 16640   // 16 * HROW

// ws layout (bytes)
#define WP_OFF     ((size_t)H_ * XPITCH)                   // xt3: bf16 [h][pitch]
#define CINV_OFF   (WP_OFF + (size_t)COUT * KTOT * 2)
#define ZERO_OFF   (CINV_OFF + 7424)                       // 512-B zero page (256-B aligned)
#define SRCOFF_OFF (ZERO_OFF + 1024)                       // u32 [H][8] gather row offsets
#define INVOFF 0xFFFFFFFFu

#define PIN4(v) asm volatile("" : "+v"(v))

typedef __attribute__((address_space(1))) unsigned int as1_u32;
typedef __attribute__((address_space(3))) unsigned int as3_u32;
static __device__ __forceinline__ void ld16_to_lds(const void* g, void* l) {
    __builtin_amdgcn_global_load_lds((const as1_u32*)g, (as3_u32*)l, 16, 0, 0);
}

static __device__ inline u16 f32_to_bf16(float f) {
    u32 u = __float_as_uint(f);
    u32 r = (u + 0x7FFFu + ((u >> 16) & 1u)) >> 16;
    return (u16)r;
}

// ---- K1 (fused): transpose x f32 [bc][h] -> xt3 bf16 [h][bc] (pitch 8448),
// plus weight-pack / inverse-counts / zero-page / gather-offset table in the
// blockIdx.y==64 stripe. (R8-verified structure; only the pitch changed.)
__global__ __launch_bounds__(256) void k_prep(const float* __restrict__ x,
                                              const float* __restrict__ wc,
                                              const float* __restrict__ wn,
                                              const int* __restrict__ nbr,
                                              u16* __restrict__ xt3,
                                              u16* __restrict__ wp,
                                              float* __restrict__ cInvG,
                                              u32* __restrict__ zeroPg,
                                              u32* __restrict__ srcOff) {
    int tid = threadIdx.x;
    if (blockIdx.y == 64) {            // ---- pack stripe (29 blocks, strided)
        for (int tg = blockIdx.x * 256 + tid; tg < COUT * KTOT; tg += 29 * 256) {
            if (tg < 128) zeroPg[tg] = 0u;           // 512-B zero page
            if (tg < H_) {
                int cnt = 1;
#pragma unroll
                for (int j = 0; j < KNB; ++j) cnt += (nbr[tg * KNB + j] >= 0) ? 1 : 0;
                cInvG[tg] = 1.0f / (float)cnt;
            }
            if (tg < H_ * 8) {
                int h = tg >> 3, s = tg & 7;
                u32 e;
                if (s == 0) e = (u32)h * (u32)XPITCH;
                else if (s <= 6) {
                    int n = nbr[h * KNB + (s - 1)];
                    e = (n >= 0) ? (u32)n * (u32)XPITCH : INVOFF;
                } else e = INVOFF;
                srcOff[tg] = e;
            }
            int o = tg / KTOT;
            int rem = tg - o * KTOT;
            int s = rem >> 6, c = rem & 63;
            float v = (s == 0) ? wc[o * CIN + c]
                               : wn[(o * CIN + c) * KNB + (s - 1)];
            wp[tg] = f32_to_bf16(v);
        }
        return;
    }
    // ---- transpose stripe: tile = u32 (bc even|odd packed), stride 34
    __shared__ u32 t32[64][34];
    int h0  = blockIdx.x * 64;
    int bc0 = blockIdx.y * 64;
    int lh = tid & 15;                 // h-quad (4 h per thread)
    int rq = tid >> 4;                 // 0..15 rowpair sub-index
    bool safe = (h0 + 64 <= H_);
#pragma unroll
    for (int it = 0; it < 2; ++it) {
        int rp = it * 16 + rq;         // rowpair 0..31 -> rows 2rp, 2rp+1
        size_t r0 = (size_t)(bc0 + rp * 2) * H_;
        size_t r1 = r0 + H_;
        int h = h0 + lh * 4;
        u32 p[4];
        if (safe) {
            floatx4u f0 = *(const floatx4u*)(x + r0 + h);
            floatx4u f1 = *(const floatx4u*)(x + r1 + h);
#pragma unroll
            for (int j = 0; j < 4; ++j)
                p[j] = (u32)f32_to_bf16(f0[j]) | ((u32)f32_to_bf16(f1[j]) << 16);
        } else {
#pragma unroll
            for (int j = 0; j < 4; ++j) {
                int hh = h + j;
                u16 a = 0, b = 0;
                if (hh < H_) { a = f32_to_bf16(x[r0 + hh]); b = f32_to_bf16(x[r1 + hh]); }
                p[j] = (u32)a | ((u32)b << 16);
            }
        }
#pragma unroll
        for (int j = 0; j < 4; ++j) t32[lh * 4 + j][rp] = p[j];
    }
    __syncthreads();
    int bg = tid & 7;                  // bc-octet
    int hb = tid >> 3;                 // 0..31
#pragma unroll
    for (int ii = 0; ii < 2; ++ii) {
        int hl = ii * 32 + hb;
        int hh = h0 + hl;
        uint2 qa = *(const uint2*)&t32[hl][bg * 4];
        uint2 qb = *(const uint2*)&t32[hl][bg * 4 + 2];
        u32x4 q = {qa.x, qa.y, qb.x, qb.y};
        if (hh < H_)
            *(u32x4*)(xt3 + (size_t)hh * XPITCH2 + bc0 + bg * 8) = q;
    }
}

// ---- K3: PERSISTENT gather-GEMM (R8-verified, best-known) -----------------
// grid = 512 = 32 bp x 16 slots — 2 blocks/CU, all co-resident, XCD = bp&7
// pinned for block lifetime (bp slice L2-hot). Slot j -> hs = j, j+16.
// Depth-3 / 4-buffer / counted-vmcnt ladder verbatim.
__global__ __launch_bounds__(256, 2) void k_main(const u16* __restrict__ xt3,
                                                 const u16* __restrict__ wp,
                                                 const float* __restrict__ bias,
                                                 const float* __restrict__ cInvG,
                                                 const u32* __restrict__ srcOff,
                                                 float* __restrict__ out) {
    __shared__ __align__(16) char LDS[4 * HBUFSZ];

    int tid  = threadIdx.x;
    int gbl  = blockIdx.x;
    int bp   = gbl & 31;          // b-pair, FIXED for block lifetime; XCD = bp&7
    int slot = gbl >> 5;          // 0..15
    int b0   = bp * 2;

    int lane = tid & 63;
    int wave = tid >> 6;          // 0..3
    int col  = lane & 15;
    int quad = lane >> 4;
    int m0w  = wave * 32;
    int lane16 = lane & 15;
    int ssub = lane >> 4;
    int bl   = lane16 >> 3;
    int chunk = lane16 & 7;

    const char* xb = (const char*)xt3;   // == d_ws base; all offsets relative

    // A fragments (weights): A[m=col][k=quad*8+j]; 112 regs, pinned.
    u32x4 afrag[2][NSTEPS];
#pragma unroll
    for (int mt = 0; mt < 2; ++mt) {
        int o = m0w + mt * 16 + col;
#pragma unroll
        for (int kk = 0; kk < NSTEPS; ++kk)
            afrag[mt][kk] = *(const u32x4*)(wp + o * KTOT + kk * 32 + quad * 8);
    }
#pragma unroll
    for (int mt = 0; mt < 2; ++mt)
#pragma unroll
        for (int kk = 0; kk < NSTEPS; ++kk)
            PIN4(afrag[mt][kk]);

    float biasv[2][4];
#pragma unroll
    for (int mt = 0; mt < 2; ++mt)
#pragma unroll
        for (int r = 0; r < 4; ++r)
            biasv[mt][r] = bias[m0w + mt * 16 + quad * 4 + r];

    u32 colOff = (u32)((b0 + bl) * 128 + chunk * 16);
    u32 zOff   = (u32)ZERO_OFF + (u32)(lane16 * 16);

    int rb0 = col * HROW + quad * 16;
    int rb1 = rb0 + 128;
    char* bufA0 = LDS;
    char* bufA1 = LDS + HBUFSZ;
    char* bufA2 = LDS + 2 * HBUFSZ;
    char* bufA3 = LDS + 3 * HBUFSZ;

#define SGH(t, sg, bufp) do {                                                 \
    char* _d = (bufp) + (wave * 4) * HROW;                                    \
    _Pragma("unroll")                                                         \
    for (int _i = 0; _i < 4; ++_i)                                            \
        ld16_to_lds(xb + offs[t][sg][_i], _d + _i * HROW);                    \
} while (0)

#define CA(accv, bufp) do {  /* k-steps 0..7, zero-init */                    \
    _Pragma("unroll") for (int _m = 0; _m < 2; ++_m)                          \
    _Pragma("unroll") for (int _n = 0; _n < 2; ++_n)                          \
        accv[_m][_n] = (floatx4){0.0f, 0.0f, 0.0f, 0.0f};                     \
    __builtin_amdgcn_s_setprio(1);                                            \
    _Pragma("unroll")                                                         \
    for (int kk = 0; kk < 8; ++kk) {                                          \
        int koff = (kk >> 1) * 256 + (kk & 1) * 64;                           \
        bf16x8 bfa = *(const bf16x8*)((bufp) + rb0 + koff);                   \
        bf16x8 bfb = *(const bf16x8*)((bufp) + rb1 + koff);                   \
        bf16x8 a0 = __builtin_bit_cast(bf16x8, afrag[0][kk]);                 \
        bf16x8 a1 = __builtin_bit_cast(bf16x8, afrag[1][kk]);                 \
        accv[0][0] = __builtin_amdgcn_mfma_f32_16x16x32_bf16(a0, bfa, accv[0][0], 0, 0, 0); \
        accv[1][0] = __builtin_amdgcn_mfma_f32_16x16x32_bf16(a1, bfa, accv[1][0], 0, 0, 0); \
        accv[0][1] = __builtin_amdgcn_mfma_f32_16x16x32_bf16(a0, bfb, accv[0][1], 0, 0, 0); \
        accv[1][1] = __builtin_amdgcn_mfma_f32_16x16x32_bf16(a1, bfb, accv[1][1], 0, 0, 0); \
    }                                                                         \
    __builtin_amdgcn_s_setprio(0);                                            \
} while (0)

#define CB(accv, bufp) do {  /* k-steps 8..13, accumulate */                  \
    __builtin_amdgcn_s_setprio(1);                                            \
    _Pragma("unroll")                                                         \
    for (int kk = 8; kk < 14; ++kk) {                                         \
        int koff = ((kk - 8) >> 1) * 256 + (kk & 1) * 64;                     \
        bf16x8 bfa = *(const bf16x8*)((bufp) + rb0 + koff);                   \
        bf16x8 bfb = *(const bf16x8*)((bufp) + rb1 + koff);                   \
        bf16x8 a0 = __builtin_bit_cast(bf16x8, afrag[0][kk]);                 \
        bf16x8 a1 = __builtin_bit_cast(bf16x8, afrag[1][kk]);                 \
        accv[0][0] = __builtin_amdgcn_mfma_f32_16x16x32_bf16(a0, bfa, accv[0][0], 0, 0, 0); \
        accv[1][0] = __builtin_amdgcn_mfma_f32_16x16x32_bf16(a1, bfa, accv[1][0], 0, 0, 0); \
        accv[0][1] = __builtin_amdgcn_mfma_f32_16x16x32_bf16(a0, bfb, accv[0][1], 0, 0, 0); \
        accv[1][1] = __builtin_amdgcn_mfma_f32_16x16x32_bf16(a1, bfb, accv[1][1], 0, 0, 0); \
    }                                                                         \
    __builtin_amdgcn_s_setprio(0);                                            \
} while (0)

// Pair epilogue via wave-private E overlay in a freed half-buffer: writes
// XOR-swizzled by (o&7), conflict-free b128 readback, 8 float4 stores/lane
// (128-B segments). BND (final epilogue of final hs only) masks the ragged
// float — uncounted position, ladder counts stay exact.
#define EPI(pp, a0v, a1v, Ebuf, BND) do {                                     \
    float* _E = (float*)((Ebuf) + (wave * 4) * HROW);                         \
    int _o8 = lane >> 3, _h4 = lane & 7;                                      \
    _Pragma("unroll")                                                         \
    for (int _nt = 0; _nt < 2; ++_nt) {                                       \
        asm volatile("s_waitcnt lgkmcnt(0)" ::: "memory");                    \
        _Pragma("unroll") for (int _mt = 0; _mt < 2; ++_mt)                   \
        _Pragma("unroll") for (int _r = 0; _r < 4; ++_r) {                    \
            int _ol = _mt * 16 + quad * 4 + _r;                               \
            int _x0 = ((col >> 2) ^ (_ol & 7));                               \
            int _x1 = (((16 + col) >> 2) ^ (_ol & 7));                        \
            _E[_ol * 32 + (_x0 << 2) + (col & 3)] =                           \
                a0v[_mt][_nt][_r] * icv[(pp) * 2]     + biasv[_mt][_r];       \
            _E[_ol * 32 + (_x1 << 2) + (col & 3)] =                           \
                a1v[_mt][_nt][_r] * icv[(pp) * 2 + 1] + biasv[_mt][_r];       \
        }                                                                     \
        asm volatile("s_waitcnt lgkmcnt(0)" ::: "memory");                    \
        _Pragma("unroll")                                                     \
        for (int _q = 0; _q < 4; ++_q) {                                      \
            int _ol = _q * 8 + _o8;                                           \
            floatx4 _v = *(const floatx4*)(_E + _ol * 32 + ((_h4 ^ (_ol & 7)) << 2)); \
            int _hh = h0 + (pp) * 32 + _h4 * 4;                               \
            float* _dst = out + (size_t)(b0 + _nt) * ((size_t)COUT * H_)      \
                        + (size_t)(m0w + _ol) * H_ + _hh;                     \
            if (!(BND)) {                                                     \
                *(floatx4u*)_dst = _v;                                        \
            } else {                                                          \
                _Pragma("unroll") for (int _e = 0; _e < 4; ++_e)              \
                    if (_hh + _e < H_) _dst[_e] = _v[_e];                     \
            }                                                                 \
        }                                                                     \
    }                                                                         \
} while (0)

#define VW(n)  asm volatile("s_waitcnt vmcnt(" #n ") lgkmcnt(0)" ::: "memory")
#define BAR()  __builtin_amdgcn_s_barrier()

    floatx4 acc0[2][2], acc1[2][2];
    int nhs = (slot + 16 <= 28) ? 2 : 1;

    for (int q = 0; q < nhs; ++q) {
        int hs = slot + q * 16;       // 0..28
        int h0 = hs * 64;
        bool bnd = (hs == 28);

        float icv[4];
#pragma unroll
        for (int t = 0; t < 4; ++t) {
            int hic = h0 + t * 16 + col;
            icv[t] = cInvG[hic < H_ ? hic : 0];
        }
        u32 offs[4][2][4];
#pragma unroll
        for (int t = 0; t < 4; ++t)
#pragma unroll
            for (int sg = 0; sg < 2; ++sg)
#pragma unroll
                for (int i = 0; i < 4; ++i) {
                    int hh = h0 + t * 16 + wave * 4 + i;
                    int s  = sg * 4 + ssub;
                    u32 e = (hh < H_) ? srcOff[hh * 8 + s] : INVOFF;
                    offs[t][sg][i] = (e == INVOFF) ? zOff : (e + colOff);
                }

        // ---- R3-verified ladder (verbatim) ----
        SGH(0, 0, bufA0);                 // S0
        SGH(0, 1, bufA1);                 // S1
        SGH(1, 0, bufA2);                 // S2

        VW(8);  BAR(); SGH(1, 1, bufA3);  CA(acc0, bufA0);   // ph0
        VW(8);  BAR(); SGH(2, 0, bufA0);  CB(acc0, bufA1);   // ph1
        VW(8);  BAR(); SGH(2, 1, bufA1);  CA(acc1, bufA2);   // ph2
        VW(8);  BAR();                    CB(acc1, bufA3);   // ph3
        EPI(0, acc0, acc1, bufA2, false);
        VW(12); BAR(); SGH(3, 0, bufA2);  CA(acc0, bufA0);   // ph4
        VW(12); BAR(); SGH(3, 1, bufA3);  CB(acc0, bufA1);   // ph5
        VW(4);  BAR();                    CA(acc1, bufA2);   // ph6
        VW(0);  BAR();                    CB(acc1, bufA3);   // ph7
        EPI(1, acc0, acc1, bufA2, bnd);

        if (q + 1 < nhs) { VW(0); BAR(); }
    }

#undef SGH
#undef CA
#undef CB
#undef EPI
#undef VW
#undef BAR
}

extern "C" void kernel_launch(void* const* d_in, const int* in_sizes, int n_in,
                              void* d_out, int out_size, void* d_ws, size_t ws_size,
                              hipStream_t stream) {
    const float* x    = (const float*)d_in[0];   // f32 [64,64,1855]
    const int*   nbr  = (const int*)d_in[1];     // int32 [1855,6]
    const float* wc   = (const float*)d_in[2];   // f32 [128,64]
    const float* wn   = (const float*)d_in[3];   // f32 [128,64,6]
    const float* bias = (const float*)d_in[4];   // f32 [128]

    u16*   xt3    = (u16*)d_ws;
    u16*   wp     = (u16*)((char*)d_ws + WP_OFF);
    float* cInvG  = (float*)((char*)d_ws + CINV_OFF);
    u32*   zeroPg = (u32*)((char*)d_ws + ZERO_OFF);
    u32*   srcOff = (u32*)((char*)d_ws + SRCOFF_OFF);

    k_prep<<<dim3(29, 65), dim3(256), 0, stream>>>(
        x, wc, wn, nbr, xt3, wp, cInvG, zeroPg, srcOff);
    k_main<<<dim3(512), dim3(256), 0, stream>>>(
        xt3, wp, bias, cInvG, srcOff, (float*)d_out);
}